// Round 1
// baseline (318.594 us; speedup 1.0000x reference)
//
#include <hip/hip_runtime.h>
#include <hip/hip_bf16.h>
#include <cstdint>

typedef __attribute__((ext_vector_type(8))) __bf16 bf16v8;
typedef __attribute__((ext_vector_type(4))) float f32x4;
typedef __attribute__((ext_vector_type(4))) unsigned short ushort4v;
typedef __attribute__((ext_vector_type(8))) unsigned short ushort8v;

#define BB 8
#define NN 2048
#define DD 768

__device__ __forceinline__ float b2f(unsigned short u) {
  union { unsigned int i; float f; } c; c.i = ((unsigned int)u) << 16; return c.f;
}
__device__ __forceinline__ unsigned short f2b(float f) {
  union { float f; unsigned int i; } c; c.f = f;
  unsigned int u = c.i;
  return (unsigned short)((u + 0x7fffu + ((u >> 16) & 1u)) >> 16);
}

// ---------------- LayerNorm: f32 [16384][768] -> bf16 ----------------
__global__ __launch_bounds__(256) void ln_kernel(const float* __restrict__ x,
                                                 const float* __restrict__ gamma,
                                                 const float* __restrict__ beta,
                                                 unsigned short* __restrict__ xb) {
  int row = blockIdx.x;
  const float* xr = x + (size_t)row * DD;
  int t = threadIdx.x;
  float a0 = xr[t], a1 = xr[t + 256], a2 = xr[t + 512];
  float s = a0 + a1 + a2;
  float q = a0 * a0 + a1 * a1 + a2 * a2;
  for (int o = 32; o > 0; o >>= 1) { s += __shfl_xor(s, o); q += __shfl_xor(q, o); }
  __shared__ float red[2][4];
  int w = t >> 6, lane = t & 63;
  if (lane == 0) { red[0][w] = s; red[1][w] = q; }
  __syncthreads();
  s = red[0][0] + red[0][1] + red[0][2] + red[0][3];
  q = red[1][0] + red[1][1] + red[1][2] + red[1][3];
  float mean = s * (1.0f / DD);
  float var = q * (1.0f / DD) - mean * mean;
  float inv = rsqrtf(var + 1e-5f);
  unsigned short* o0 = xb + (size_t)row * DD;
  o0[t]       = f2b((a0 - mean) * inv * gamma[t]       + beta[t]);
  o0[t + 256] = f2b((a1 - mean) * inv * gamma[t + 256] + beta[t + 256]);
  o0[t + 512] = f2b((a2 - mean) * inv * gamma[t + 512] + beta[t + 512]);
}

// ------------- Weight concat/convert: Wcat[2304][768] bf16, scale folded into Wq -------------
__global__ __launch_bounds__(256) void wconvert(const float* __restrict__ Wq,
                                                const float* __restrict__ Wk,
                                                const float* __restrict__ Wv,
                                                unsigned short* __restrict__ Wcat) {
  int i = blockIdx.x * 256 + threadIdx.x;
  const int dd = DD * DD;
  if (i >= 3 * dd) return;
  float v;
  if (i < dd)           v = Wq[i] * 0.03608439182435161f;   // 1/sqrt(768)
  else if (i < 2 * dd)  v = Wk[i - dd];
  else                  v = Wv[i - 2 * dd];
  Wcat[i] = f2b(v);
}

// ---------------- async global->LDS (16B per lane, wave-uniform LDS base) ----------------
__device__ __forceinline__ void gload_lds16(const void* g, void* l) {
  __builtin_amdgcn_global_load_lds(
      (const __attribute__((address_space(1))) void*)g,
      (__attribute__((address_space(3))) void*)(unsigned)(uintptr_t)l,
      16, 0, 0);
}

// ---------------- 128x128 bf16 GEMM (both operands K-contiguous, C = A * B^T) ----------------
// MODE 0: QKV projection epilogue (route to Q / K / V-transposed)
// MODE 1: bf16 store (scores)
// MODE 2: f32 store (context)
template <int MODE>
__global__ __launch_bounds__(256) void gemm_bt(
    const unsigned short* __restrict__ A, const unsigned short* __restrict__ Bm,
    unsigned short* __restrict__ Cq, unsigned short* __restrict__ Ck,
    unsigned short* __restrict__ Cv, float* __restrict__ Cf,
    int K, int lda, int ldb,
    long aStride, long bStride, long cStride) {
  __shared__ alignas(16) unsigned short As[128 * 64];
  __shared__ alignas(16) unsigned short Bs[128 * 64];

  const int t = threadIdx.x;
  const int n0 = blockIdx.x * 128;
  const int m0 = blockIdx.y * 128;
  const int bz = blockIdx.z;
  const unsigned short* Ab = A + (size_t)bz * aStride;
  const unsigned short* Bb = Bm + (size_t)bz * bStride;

  const int lane = t & 63;
  const int w = t >> 6;
  const int wm = w >> 1, wn = w & 1;
  const int frow = lane & 15;
  const int kcol = (lane >> 4) * 8;
  const int ldsWaveBase = (t & 192) * 8;  // elements; wave-uniform
  const int srow = t >> 3;                // 0..31 within a 32-row staging slice
  const int scol = (t & 7) * 8;

  f32x4 acc[4][4] = {};

  for (int k0 = 0; k0 < K; k0 += 64) {
    __syncthreads();
#pragma unroll
    for (int c = 0; c < 4; ++c) {
      gload_lds16(Ab + (size_t)(m0 + c * 32 + srow) * lda + k0 + scol,
                  &As[c * 2048 + ldsWaveBase]);
      gload_lds16(Bb + (size_t)(n0 + c * 32 + srow) * ldb + k0 + scol,
                  &Bs[c * 2048 + ldsWaveBase]);
    }
    asm volatile("s_waitcnt vmcnt(0)" ::: "memory");
    __syncthreads();
#pragma unroll
    for (int ks = 0; ks < 2; ++ks) {
      bf16v8 a[4], b[4];
#pragma unroll
      for (int i = 0; i < 4; ++i)
        a[i] = *(const bf16v8*)&As[(wm * 64 + i * 16 + frow) * 64 + ks * 32 + kcol];
#pragma unroll
      for (int j = 0; j < 4; ++j)
        b[j] = *(const bf16v8*)&Bs[(wn * 64 + j * 16 + frow) * 64 + ks * 32 + kcol];
#pragma unroll
      for (int i = 0; i < 4; ++i)
#pragma unroll
        for (int j = 0; j < 4; ++j)
          acc[i][j] = __builtin_amdgcn_mfma_f32_16x16x32_bf16(a[i], b[j], acc[i][j], 0, 0, 0);
    }
  }

  // Epilogue. C/D layout: col = lane&15, row = (lane>>4)*4 + reg  [HW-verified]
  const int r0 = (lane >> 4) * 4;
  const int c0 = lane & 15;
  const int mrow = m0 + wm * 64 + r0;   // + i*16 + r
  const int ncol = n0 + wn * 64 + c0;   // + j*16

  if (MODE == 0) {
    if (n0 < 1536) {  // Q or K region (block-uniform since 128 | 768)
      unsigned short* dst = (n0 < 768) ? Cq : Ck;
      const int cb = (n0 < 768) ? 0 : 768;
#pragma unroll
      for (int i = 0; i < 4; ++i)
#pragma unroll
        for (int j = 0; j < 4; ++j)
#pragma unroll
          for (int r = 0; r < 4; ++r)
            dst[(size_t)(mrow + i * 16 + r) * DD + (ncol + j * 16 - cb)] = f2b(acc[i][j][r]);
    } else {  // V region: store transposed Vt[b][e][n]
#pragma unroll
      for (int i = 0; i < 4; ++i) {
        int row = mrow + i * 16;          // global token index = b*2048 + n
        int bb = row >> 11, nn = row & 2047;
#pragma unroll
        for (int j = 0; j < 4; ++j) {
          int e = ncol + j * 16 - 1536;
          ushort4v pk;
#pragma unroll
          for (int r = 0; r < 4; ++r) pk[r] = f2b(acc[i][j][r]);
          *(ushort4v*)&Cv[((size_t)(bb * DD + e)) * NN + nn] = pk;
        }
      }
    }
  } else if (MODE == 1) {
    unsigned short* dst = Cq + (size_t)bz * cStride;
#pragma unroll
    for (int i = 0; i < 4; ++i)
#pragma unroll
      for (int j = 0; j < 4; ++j)
#pragma unroll
        for (int r = 0; r < 4; ++r)
          dst[(size_t)(mrow + i * 16 + r) * NN + (ncol + j * 16)] = f2b(acc[i][j][r]);
  } else {
    float* dst = Cf + (size_t)bz * cStride;
#pragma unroll
    for (int i = 0; i < 4; ++i)
#pragma unroll
      for (int j = 0; j < 4; ++j)
#pragma unroll
        for (int r = 0; r < 4; ++r)
          dst[(size_t)(mrow + i * 16 + r) * DD + (ncol + j * 16)] = acc[i][j][r];
  }
}

// ---------------- masked softmax, in-place on bf16 S rows ----------------
__global__ __launch_bounds__(256) void softmax_mask(unsigned short* __restrict__ S,
                                                    const int* __restrict__ mask) {
  int row = blockIdx.x;            // 0..16383
  int bb = row >> 11;
  unsigned short* sr = S + (size_t)row * NN;
  const int* mr = mask + bb * NN;
  int t = threadIdx.x;

  ushort8v pk = *(const ushort8v*)&sr[t * 8];
  float v[8];
  int msk[8];
#pragma unroll
  for (int j = 0; j < 8; ++j) msk[j] = mr[t * 8 + j];
  float mx = -1e30f;
#pragma unroll
  for (int j = 0; j < 8; ++j) {
    v[j] = b2f(pk[j]);
    if (!msk[j]) mx = fmaxf(mx, v[j]);
  }
  for (int o = 32; o > 0; o >>= 1) mx = fmaxf(mx, __shfl_xor(mx, o));
  __shared__ float redm[4], reds[4];
  int w = t >> 6, lane = t & 63;
  if (lane == 0) redm[w] = mx;
  __syncthreads();
  mx = fmaxf(fmaxf(redm[0], redm[1]), fmaxf(redm[2], redm[3]));

  float e[8];
  float sum = 0.f;
#pragma unroll
  for (int j = 0; j < 8; ++j) {
    e[j] = msk[j] ? 0.f : __expf(v[j] - mx);
    sum += e[j];
  }
  for (int o = 32; o > 0; o >>= 1) sum += __shfl_xor(sum, o);
  if (lane == 0) reds[w] = sum;
  __syncthreads();
  sum = reds[0] + reds[1] + reds[2] + reds[3];
  float inv = 1.0f / sum;

  ushort8v op;
#pragma unroll
  for (int j = 0; j < 8; ++j) op[j] = f2b(e[j] * inv);
  *(ushort8v*)&sr[t * 8] = op;
}

extern "C" void kernel_launch(void* const* d_in, const int* in_sizes, int n_in,
                              void* d_out, int out_size, void* d_ws, size_t ws_size,
                              hipStream_t stream) {
  const float* features = (const float*)d_in[0];
  const int* mask       = (const int*)d_in[1];
  const float* Wq       = (const float*)d_in[2];
  const float* Wk       = (const float*)d_in[3];
  const float* Wv       = (const float*)d_in[4];
  const float* gamma    = (const float*)d_in[5];
  const float* beta     = (const float*)d_in[6];
  float* out = (float*)d_out;

  char* ws = (char*)d_ws;
  size_t off = 0;
  auto alloc = [&](size_t bytes) {
    char* p = ws + off;
    off += (bytes + 255) & ~(size_t)255;
    return p;
  };
  unsigned short* Wcat = (unsigned short*)alloc((size_t)2304 * DD * 2);
  unsigned short* Qb   = (unsigned short*)alloc((size_t)BB * NN * DD * 2);
  unsigned short* Kb   = (unsigned short*)alloc((size_t)BB * NN * DD * 2);
  unsigned short* Vt   = (unsigned short*)alloc((size_t)BB * NN * DD * 2);
  // S (67 MB) aliases the X buffer region: X is dead once GEMM0 completes.
  char* last = alloc((size_t)BB * NN * NN * 2);
  unsigned short* Sb = (unsigned short*)last;
  unsigned short* Xb = (unsigned short*)last;  // first 25 MB of the S region

  ln_kernel<<<BB * NN, 256, 0, stream>>>(features, gamma, beta, Xb);
  wconvert<<<(3 * DD * DD + 255) / 256, 256, 0, stream>>>(Wq, Wk, Wv, Wcat);

  // QKV projection: [16384,768] x [2304,768]^T
  gemm_bt<0><<<dim3(2304 / 128, (BB * NN) / 128, 1), 256, 0, stream>>>(
      Xb, Wcat, Qb, Kb, Vt, nullptr, DD, DD, DD, 0, 0, 0);

  // Scores: per batch [2048,768] x [2048,768]^T -> S bf16
  gemm_bt<1><<<dim3(NN / 128, NN / 128, BB), 256, 0, stream>>>(
      Qb, Kb, Sb, nullptr, nullptr, nullptr, DD, DD, DD,
      (long)NN * DD, (long)NN * DD, (long)NN * NN);

  softmax_mask<<<BB * NN, 256, 0, stream>>>(Sb, mask);

  // Context: per batch P[2048,2048] x Vt[768,2048]^T -> f32 out
  gemm_bt<2><<<dim3(DD / 128, NN / 128, BB), 256, 0, stream>>>(
      Sb, Vt, nullptr, nullptr, nullptr, out, NN, NN, NN,
      (long)NN * NN, (long)DD * NN, (long)NN * DD);
}

// Round 2
// 243.184 us; speedup vs baseline: 1.3101x; 1.3101x over previous
//
#include <hip/hip_runtime.h>
#include <hip/hip_bf16.h>
#include <cstdint>

typedef __attribute__((ext_vector_type(8))) __bf16 bf16v8;
typedef __attribute__((ext_vector_type(4))) float f32x4;
typedef __attribute__((ext_vector_type(4))) unsigned short ushort4v;
typedef __attribute__((ext_vector_type(8))) unsigned short ushort8v;

#define BB 8
#define NN 2048
#define DD 768

__device__ __forceinline__ float b2f(unsigned short u) {
  union { unsigned int i; float f; } c; c.i = ((unsigned int)u) << 16; return c.f;
}
__device__ __forceinline__ unsigned short f2b(float f) {
  union { float f; unsigned int i; } c; c.f = f;
  unsigned int u = c.i;
  return (unsigned short)((u + 0x7fffu + ((u >> 16) & 1u)) >> 16);
}

// ---------------- LayerNorm: f32 [16384][768] -> bf16 ----------------
__global__ __launch_bounds__(256) void ln_kernel(const float* __restrict__ x,
                                                 const float* __restrict__ gamma,
                                                 const float* __restrict__ beta,
                                                 unsigned short* __restrict__ xb) {
  int row = blockIdx.x;
  const float* xr = x + (size_t)row * DD;
  int t = threadIdx.x;
  float a0 = xr[t], a1 = xr[t + 256], a2 = xr[t + 512];
  float s = a0 + a1 + a2;
  float q = a0 * a0 + a1 * a1 + a2 * a2;
  for (int o = 32; o > 0; o >>= 1) { s += __shfl_xor(s, o); q += __shfl_xor(q, o); }
  __shared__ float red[2][4];
  int w = t >> 6, lane = t & 63;
  if (lane == 0) { red[0][w] = s; red[1][w] = q; }
  __syncthreads();
  s = red[0][0] + red[0][1] + red[0][2] + red[0][3];
  q = red[1][0] + red[1][1] + red[1][2] + red[1][3];
  float mean = s * (1.0f / DD);
  float var = q * (1.0f / DD) - mean * mean;
  float inv = rsqrtf(var + 1e-5f);
  unsigned short* o0 = xb + (size_t)row * DD;
  o0[t]       = f2b((a0 - mean) * inv * gamma[t]       + beta[t]);
  o0[t + 256] = f2b((a1 - mean) * inv * gamma[t + 256] + beta[t + 256]);
  o0[t + 512] = f2b((a2 - mean) * inv * gamma[t + 512] + beta[t + 512]);
}

// ------------- Weight concat/convert: Wcat[2304][768] bf16, scale folded into Wq -------------
__global__ __launch_bounds__(256) void wconvert(const float* __restrict__ Wq,
                                                const float* __restrict__ Wk,
                                                const float* __restrict__ Wv,
                                                unsigned short* __restrict__ Wcat) {
  int i = blockIdx.x * 256 + threadIdx.x;
  const int dd = DD * DD;
  if (i >= 3 * dd) return;
  float v;
  if (i < dd)           v = Wq[i] * 0.03608439182435161f;   // 1/sqrt(768)
  else if (i < 2 * dd)  v = Wk[i - dd];
  else                  v = Wv[i - 2 * dd];
  Wcat[i] = f2b(v);
}

// ---------------- async global->LDS (16B per lane, wave-uniform LDS base) ----------------
__device__ __forceinline__ void gload_lds16(const void* g, void* l) {
  __builtin_amdgcn_global_load_lds(
      (const __attribute__((address_space(1))) void*)g,
      (__attribute__((address_space(3))) void*)(unsigned)(uintptr_t)l,
      16, 0, 0);
}

#define MFMA16(dst_j0, aarr, barr)                                                      \
  _Pragma("unroll")                                                                     \
  for (int i = 0; i < 8; ++i) {                                                         \
    acc[i][dst_j0]     = __builtin_amdgcn_mfma_f32_16x16x32_bf16(aarr[i], barr[dst_j0],     acc[i][dst_j0],     0, 0, 0); \
    acc[i][dst_j0 + 1] = __builtin_amdgcn_mfma_f32_16x16x32_bf16(aarr[i], barr[dst_j0 + 1], acc[i][dst_j0 + 1], 0, 0, 0); \
  }

// ---------------- 256x256 8-phase bf16 GEMM, C = A * B^T (both operands K-contiguous) ----
// 512 threads = 8 waves (2 M-halves x 4 N-groups); BK=64; LDS 128 KiB double-buffered.
// LDS K-rows XOR-swizzled (3-bit colgroup swizzle) both-sides: pre-swizzled global source
// for global_load_lds (linear dest) + swizzled ds_read address.
// MODE 0: QKV projection epilogue (Q / K / V-transposed)   MODE 1: bf16 store   MODE 2: f32 store
template <int MODE>
__global__ __launch_bounds__(512, 2) void gemm256(
    const unsigned short* __restrict__ A, const unsigned short* __restrict__ Bm,
    unsigned short* __restrict__ Cq, unsigned short* __restrict__ Ck,
    unsigned short* __restrict__ Cv, float* __restrict__ Cf,
    int K, int lda, int ldb,
    long aStride, long bStride, long cStride) {
  extern __shared__ unsigned short smem[];      // 65536 elems = 131072 B
  unsigned short* As = smem;                    // [2 buf][256 rows][64] (A tile)
  unsigned short* Bs = smem + 32768;            // [2 buf][256 rows][64] (B tile)

  const int t = threadIdx.x;
  int bx = blockIdx.x, by = blockIdx.y, bz = blockIdx.z;
  {  // bijective XCD swizzle (all grids are %8==0)
    const int gx = gridDim.x, gy = gridDim.y;
    const int nwg = gx * gy * (int)gridDim.z;
    int id = bx + gx * (by + gy * bz);
    int sw = (id & 7) * (nwg >> 3) + (id >> 3);
    bx = sw % gx; int r2 = sw / gx;
    by = r2 % gy; bz = r2 / gy;
  }
  const int n0 = bx * 256, m0 = by * 256;
  const unsigned short* Ab = A + (size_t)bz * aStride;
  const unsigned short* Bb = Bm + (size_t)bz * bStride;

  const int lane = t & 63;
  const int w = t >> 6;
  const int wm = w >> 2, wn = w & 3;          // 2 x 4 wave grid; per-wave out 128x64
  const int frow = lane & 15;
  const int arowb = (wm * 128 + frow) * 64;   // + i*1024
  const int browb = (wn * 64 + frow) * 64;    // + j*1024
  // swizzled column-group offsets (elements) for kslice 0/1
  const int ck0 = (((lane >> 4) ^ (frow & 7)) * 8);
  const int ck1 = ((4 + (lane >> 4)) ^ (frow & 7)) * 8;

  // staging: 2 gload_lds per half-tile (128 rows x 64 cols); pre-swizzled global col
  const int srow = t >> 3;                          // 0..63
  const int gcol = ((t & 7) ^ (srow & 7)) * 8;      // inverse(=same) swizzle on source
  const int ldsw = (t >> 6) << 9;                   // wave-uniform LDS base (elems)
  const unsigned short* Asrc = Ab + (size_t)(m0 + srow) * lda + gcol;
  const unsigned short* Bsrc = Bb + (size_t)(n0 + srow) * ldb + gcol;

  auto stageA = [&](int tk, int h) {
    const unsigned short* s = Asrc + (size_t)(h * 128) * lda + tk * 64;
    unsigned short* d = &As[((tk & 1) << 14) + (h << 13) + ldsw];
    gload_lds16(s, d);
    gload_lds16(s + (size_t)64 * lda, d + 4096);
  };
  auto stageB = [&](int tk, int h) {
    const unsigned short* s = Bsrc + (size_t)(h * 128) * ldb + tk * 64;
    unsigned short* d = &Bs[((tk & 1) << 14) + (h << 13) + ldsw];
    gload_lds16(s, d);
    gload_lds16(s + (size_t)64 * ldb, d + 4096);
  };

  f32x4 acc[8][4] = {};
  const int NT = K >> 6;

  // prologue: tile0 complete + tile1 B-halves; keep tile1's B (4 loads) in flight
  stageA(0, 0); stageA(0, 1);
  stageB(0, 0); stageB(0, 1);
  stageB(1, 0); stageB(1, 1);
  asm volatile("s_waitcnt vmcnt(4)" ::: "memory");
  __builtin_amdgcn_s_barrier();

  for (int kt = 0; kt < NT; ++kt) {
    const int bsel = (kt & 1) << 14;
    const unsigned short* Al = As + bsel;
    const unsigned short* Bl = Bs + bsel;
    bf16v8 a[8], b0[4], b1[4];
    // ---- phase 1: read A-ks0 + B-ks0; stage A-half0 of kt+1; MFMA ks0 x N01
#pragma unroll
    for (int i = 0; i < 8; ++i) a[i] = *(const bf16v8*)&Al[arowb + i * 1024 + ck0];
#pragma unroll
    for (int j = 0; j < 4; ++j) b0[j] = *(const bf16v8*)&Bl[browb + j * 1024 + ck0];
    if (kt + 1 < NT) stageA(kt + 1, 0);
    __builtin_amdgcn_s_barrier();
    __builtin_amdgcn_s_setprio(1);
    MFMA16(0, a, b0)
    __builtin_amdgcn_s_setprio(0);
    __builtin_amdgcn_s_barrier();
    // ---- phase 2: read B-ks1; stage A-half1 of kt+1; MFMA ks0 x N23
#pragma unroll
    for (int j = 0; j < 4; ++j) b1[j] = *(const bf16v8*)&Bl[browb + j * 1024 + ck1];
    if (kt + 1 < NT) stageA(kt + 1, 1);
    __builtin_amdgcn_s_barrier();
    __builtin_amdgcn_s_setprio(1);
    MFMA16(2, a, b0)
    __builtin_amdgcn_s_setprio(0);
    // close ALL outstanding LDS-read windows before B-region is re-staged (ph3/ph4)
    asm volatile("s_waitcnt lgkmcnt(0)" ::: "memory");
    __builtin_amdgcn_sched_barrier(0);
    __builtin_amdgcn_s_barrier();
    // ---- phase 3: read A-ks1; stage B-half0 of kt+2; MFMA ks1 x N01
#pragma unroll
    for (int i = 0; i < 8; ++i) a[i] = *(const bf16v8*)&Al[arowb + i * 1024 + ck1];
    if (kt + 2 < NT) stageB(kt + 2, 0);
    __builtin_amdgcn_s_barrier();
    __builtin_amdgcn_s_setprio(1);
    MFMA16(0, a, b1)
    __builtin_amdgcn_s_setprio(0);
    __builtin_amdgcn_s_barrier();
    // ---- phase 4: stage B-half1 of kt+2; MFMA ks1 x N23; counted vmcnt at tile boundary
    if (kt + 2 < NT) stageB(kt + 2, 1);
    __builtin_amdgcn_s_barrier();
    __builtin_amdgcn_s_setprio(1);
    MFMA16(2, a, b1)
    __builtin_amdgcn_s_setprio(0);
    if (kt == NT - 2) {
      asm volatile("s_waitcnt vmcnt(0)" ::: "memory");
    } else if (kt < NT - 2) {
      asm volatile("s_waitcnt vmcnt(4)" ::: "memory");
    }
    __builtin_amdgcn_s_barrier();
  }

  // Epilogue. C/D layout: col = lane&15, row = (lane>>4)*4 + reg  [HW-verified]
  const int r0 = (lane >> 4) * 4;
  const int c0 = lane & 15;
  const int mrowB = m0 + wm * 128 + r0;   // + i*16 + r
  const int ncolB = n0 + wn * 64 + c0;    // + j*16

  if (MODE == 0) {
    if (n0 < 1536) {  // Q or K region (block-uniform: 256 | 768)
      unsigned short* dst = (n0 < 768) ? Cq : Ck;
      const int cb = (n0 < 768) ? 0 : 768;
#pragma unroll
      for (int i = 0; i < 8; ++i)
#pragma unroll
        for (int j = 0; j < 4; ++j)
#pragma unroll
          for (int r = 0; r < 4; ++r)
            dst[(size_t)(mrowB + i * 16 + r) * DD + (ncolB + j * 16 - cb)] = f2b(acc[i][j][r]);
    } else {  // V region: store transposed Vt[b][e][n]
#pragma unroll
      for (int i = 0; i < 8; ++i) {
        int row = mrowB + i * 16;          // global token index = b*2048 + n
        int bb = row >> 11, nn = row & 2047;
#pragma unroll
        for (int j = 0; j < 4; ++j) {
          int e = ncolB + j * 16 - 1536;
          ushort4v pk;
#pragma unroll
          for (int r = 0; r < 4; ++r) pk[r] = f2b(acc[i][j][r]);
          *(ushort4v*)&Cv[((size_t)(bb * DD + e)) * NN + nn] = pk;
        }
      }
    }
  } else if (MODE == 1) {
    unsigned short* dst = Cq + (size_t)bz * cStride;
#pragma unroll
    for (int i = 0; i < 8; ++i)
#pragma unroll
      for (int j = 0; j < 4; ++j)
#pragma unroll
        for (int r = 0; r < 4; ++r)
          dst[(size_t)(mrowB + i * 16 + r) * NN + (ncolB + j * 16)] = f2b(acc[i][j][r]);
  } else {
    float* dst = Cf + (size_t)bz * cStride;
#pragma unroll
    for (int i = 0; i < 8; ++i)
#pragma unroll
      for (int j = 0; j < 4; ++j)
#pragma unroll
        for (int r = 0; r < 4; ++r)
          dst[(size_t)(mrowB + i * 16 + r) * DD + (ncolB + j * 16)] = acc[i][j][r];
  }
}

// ---------------- masked softmax, in-place on bf16 S rows ----------------
__global__ __launch_bounds__(256) void softmax_mask(unsigned short* __restrict__ S,
                                                    const int* __restrict__ mask) {
  int row = blockIdx.x;            // 0..16383
  int bb = row >> 11;
  unsigned short* sr = S + (size_t)row * NN;
  const int* mr = mask + bb * NN;
  int t = threadIdx.x;

  ushort8v pk = *(const ushort8v*)&sr[t * 8];
  float v[8];
  int msk[8];
#pragma unroll
  for (int j = 0; j < 8; ++j) msk[j] = mr[t * 8 + j];
  float mx = -1e30f;
#pragma unroll
  for (int j = 0; j < 8; ++j) {
    v[j] = b2f(pk[j]);
    if (!msk[j]) mx = fmaxf(mx, v[j]);
  }
  for (int o = 32; o > 0; o >>= 1) mx = fmaxf(mx, __shfl_xor(mx, o));
  __shared__ float redm[4], reds[4];
  int w = t >> 6, lane = t & 63;
  if (lane == 0) redm[w] = mx;
  __syncthreads();
  mx = fmaxf(fmaxf(redm[0], redm[1]), fmaxf(redm[2], redm[3]));

  float e[8];
  float sum = 0.f;
#pragma unroll
  for (int j = 0; j < 8; ++j) {
    e[j] = msk[j] ? 0.f : __expf(v[j] - mx);
    sum += e[j];
  }
  for (int o = 32; o > 0; o >>= 1) sum += __shfl_xor(sum, o);
  if (lane == 0) reds[w] = sum;
  __syncthreads();
  sum = reds[0] + reds[1] + reds[2] + reds[3];
  float inv = 1.0f / sum;

  ushort8v op;
#pragma unroll
  for (int j = 0; j < 8; ++j) op[j] = f2b(e[j] * inv);
  *(ushort8v*)&sr[t * 8] = op;
}

extern "C" void kernel_launch(void* const* d_in, const int* in_sizes, int n_in,
                              void* d_out, int out_size, void* d_ws, size_t ws_size,
                              hipStream_t stream) {
  const float* features = (const float*)d_in[0];
  const int* mask       = (const int*)d_in[1];
  const float* Wq       = (const float*)d_in[2];
  const float* Wk       = (const float*)d_in[3];
  const float* Wv       = (const float*)d_in[4];
  const float* gamma    = (const float*)d_in[5];
  const float* beta     = (const float*)d_in[6];
  float* out = (float*)d_out;

  char* ws = (char*)d_ws;
  size_t off = 0;
  auto alloc = [&](size_t bytes) {
    char* p = ws + off;
    off += (bytes + 255) & ~(size_t)255;
    return p;
  };
  unsigned short* Wcat = (unsigned short*)alloc((size_t)2304 * DD * 2);
  unsigned short* Qb   = (unsigned short*)alloc((size_t)BB * NN * DD * 2);
  unsigned short* Kb   = (unsigned short*)alloc((size_t)BB * NN * DD * 2);
  unsigned short* Vt   = (unsigned short*)alloc((size_t)BB * NN * DD * 2);
  // S (67 MB) aliases the X buffer region: X is dead once GEMM0 completes.
  char* last = alloc((size_t)BB * NN * NN * 2);
  unsigned short* Sb = (unsigned short*)last;
  unsigned short* Xb = (unsigned short*)last;  // first 25 MB of the S region

  // allow 128 KiB dynamic LDS (idempotent host-side config; not a stream op)
  (void)hipFuncSetAttribute(reinterpret_cast<const void*>(&gemm256<0>),
                            hipFuncAttributeMaxDynamicSharedMemorySize, 131072);
  (void)hipFuncSetAttribute(reinterpret_cast<const void*>(&gemm256<1>),
                            hipFuncAttributeMaxDynamicSharedMemorySize, 131072);
  (void)hipFuncSetAttribute(reinterpret_cast<const void*>(&gemm256<2>),
                            hipFuncAttributeMaxDynamicSharedMemorySize, 131072);

  ln_kernel<<<BB * NN, 256, 0, stream>>>(features, gamma, beta, Xb);
  wconvert<<<(3 * DD * DD + 255) / 256, 256, 0, stream>>>(Wq, Wk, Wv, Wcat);

  // QKV projection: [16384,768] x [2304,768]^T
  gemm256<0><<<dim3(2304 / 256, (BB * NN) / 256, 1), 512, 131072, stream>>>(
      Xb, Wcat, Qb, Kb, Vt, nullptr, DD, DD, DD, 0, 0, 0);

  // Scores: per batch [2048,768] x [2048,768]^T -> S bf16
  gemm256<1><<<dim3(NN / 256, NN / 256, BB), 512, 131072, stream>>>(
      Qb, Kb, Sb, nullptr, nullptr, nullptr, DD, DD, DD,
      (long)NN * DD, (long)NN * DD, (long)NN * NN);

  softmax_mask<<<BB * NN, 256, 0, stream>>>(Sb, mask);

  // Context: per batch P[2048,2048] x Vt[768,2048]^T -> f32 out
  gemm256<2><<<dim3(DD / 256, NN / 256, BB), 512, 131072, stream>>>(
      Sb, Vt, nullptr, nullptr, nullptr, out, NN, NN, NN,
      (long)NN * NN, (long)DD * NN, (long)NN * DD);
}